// Round 6
// baseline (514.216 us; speedup 1.0000x reference)
//
#include <hip/hip_runtime.h>
#include <math.h>

// ---------------- problem constants ----------------
#define FC     65            // freq bins in H
#define NB     97            // output samples per frame (lossy irfft n)
#define KB     49            // bins actually used = NB//2+1
#define FRAME  64
#define B_     32
#define F_     4000
#define OUT_LEN ((F_ - 1) * FRAME + NB)   // 256033
#define CHUNK  31                          // OUTPUT frames per block (pair0 redundant)
#define NCHUNK 130                         // ceil(4000/31)
#define KP     100                         // padded row stride (16B-aligned rows)

// ws layout (floats), rows stacked contiguously (226 rows x 100):
//   D: rows 0..63    row j:   (cos,sin)(-2*pi*k*j/192), k=0..48, pads 98/99=0
//   W: rows 64..128  row kap: complex W matrix, pads 0
//   E: rows 129..225 row t:   (Er,Ei) with gain folded, pads 0
#define D_OFF  0
#define W_OFF  (64 * KP)
#define E_OFF  (129 * KP)

#define N_D    (64 * KB)                   // 3136
#define N_E    (97 * KB)                   // 4753
#define N_W    (65 * KB)                   // 3185
#define N_ALL  (N_D + N_E + N_W)           // 11074
#define N_PADZ (226 * 2)                   // row pad zeros
#define N_INIT (N_ALL + N_PADZ)

// ---------- single init kernel; W via fp64 recurrences (no libm in loop) ----------
__global__ void fn_init(float* __restrict__ ws) {
    int tid = blockIdx.x * blockDim.x + threadIdx.x;
    if (tid < N_D) {
        int j = tid / KB, k = tid % KB;
        double x = -(double)(k * j) / 96.0;            // theta/pi
        ws[D_OFF + j * KP + 2 * k]     = (float)cospi(x);
        ws[D_OFF + j * KP + 2 * k + 1] = (float)sinpi(x);
    } else if (tid < N_D + N_E) {
        int t2 = tid - N_D;
        int t = t2 / KB, k = t2 % KB;
        double g = 0.01 / 97.0;
        double x = 2.0 * (double)(k * t) / 97.0;       // theta/pi
        ws[E_OFF + t * KP + 2 * k]     = (float)(g * (k == 0 ? 1.0 : 2.0) * cospi(x));
        ws[E_OFF + t * KP + 2 * k + 1] = (float)(k == 0 ? 0.0 : -2.0 * g * sinpi(x));
    } else if (tid < N_ALL) {
        int t2 = tid - (N_D + N_E);
        int kap = t2 / KB, k = t2 % KB;
        double sr_ = cospi(-(double)k / 96.0), si_ = sinpi(-(double)k / 96.0);
        double er = 1.0, ei = 0.0;
        double C2 = 2.0 * cospi(2.0 * (double)kap / 129.0);
        double c_prev = cospi(-130.0 * (double)kap / 129.0);   // m = -1
        double c_cur  = cospi(-128.0 * (double)kap / 129.0);   // m = 0
        double U2 = 2.0 * cospi(2.0 / 129.0);
        double u_prev = cospi(2.0 / 129.0);                    // u(-1)
        double u_cur  = 1.0;                                   // u(0)
        double accr = 0.0, acci = 0.0;
        for (int m = 0; m < 129; m++) {
            double win = 0.5 * (1.0 - u_cur);
            double a = win * (1.0 / 129.0);
            if (kap) a *= 2.0 * c_cur;
            accr += a * er; acci += a * ei;
            double un = U2 * u_cur - u_prev; u_prev = u_cur; u_cur = un;
            double cn = C2 * c_cur - c_prev; c_prev = c_cur; c_cur = cn;
            double e2r = er * sr_ - ei * si_;
            double e2i = er * si_ + ei * sr_;
            er = e2r; ei = e2i;
        }
        ws[W_OFF + kap * KP + 2 * k]     = (float)accr;
        ws[W_OFF + kap * KP + 2 * k + 1] = (float)acci;
    } else if (tid < N_INIT) {
        int z = tid - N_ALL;
        ws[(z >> 1) * KP + 98 + (z & 1)] = 0.0f;       // row pads
    }
}

// Named scalars with LITERAL indices (hipcc SROA runs before unrolling;
// loop-variable-indexed arrays land in scratch -- proven rounds 3-5).
// Each lane owns 25 bins: even lanes k=0..24, odd lanes k=25..48 (+zero pad).
#define REPA(M) M(0) M(1) M(2) M(3) M(4) M(5) M(6) M(7) M(8) M(9) M(10) M(11)
#define REPB(M) M(12) M(13) M(14) M(15) M(16) M(17) M(18) M(19) M(20) M(21) M(22) M(23) M(24)
#define REP25(M) REPA(M) REPB(M)

// ---------- main: 1 wave/block, 32 frames (31 output + 1 redundant), lane pairs ----------
__launch_bounds__(64, 4)
__global__ void fn_main_kernel(const float* __restrict__ H,
                               const float* __restrict__ noise,
                               const float* __restrict__ ws,
                               float* __restrict__ out) {
    __shared__ float bufA[32 * 65];       // 8.3 KB, reused: noise -> H -> obuf

    int bid = blockIdx.x;
    int b = bid / NCHUNK;
    int c = bid - b * NCHUNK;
    int f0 = c * CHUNK;
    int nf = min(CHUNK, F_ - f0);
    int L = threadIdx.x;
    int p = L >> 1;                       // pair index = frame slot (0..31)
    int off = (L & 1) * 50;               // float offset into each matrix row
    int fMine = f0 - 1 + p;
    bool own = (L & 1) == 0;              // even lane owns obuf row p-1

    // ---- phase 0: stage noise, row i = frame f0-1+i (32 rows x 64, stride 65) ----
    long nbase = ((long)b * F_ + (f0 - 1)) * FRAME;
    const long nmax = (long)B_ * F_ * FRAME - 1;
#pragma unroll 1
    for (int i = 0; i < 32; i++) {
        long g = nbase + (long)i * 64 + L;
        g = g < 0 ? 0 : (g > nmax ? nmax : g);
        float v = 2.0f * noise[g] - 1.0f;
        if (c == 0 && i == 0) v = 0.0f;   // frame -1: force N=0 -> X=0
        bufA[i * 65 + L] = v;
    }
    __syncthreads();

    // ---- X state: 50 named scalar registers per lane ----
#define DECLX(k) float Nr##k = 0.0f, Ni##k = 0.0f;
    REP25(DECLX)
#undef DECLX

    // ---- phase 1: N[k] partial DFT (my 25 bins) ----
#pragma unroll 1
    for (int j = 0; j < 64; j++) {
        float n = bufA[p * 65 + j];                       // pair-broadcast
        const float* d = ws + D_OFF + j * KP + off;
#define P1(k) Nr##k = fmaf(n, d[2*(k)], Nr##k); Ni##k = fmaf(n, d[2*(k)+1], Ni##k);
        REP25(P1)
#undef P1
    }
    __syncthreads();

    // ---- phase 2: stage H (linear copy, 32*65 = 2080 floats) ----
    long hbase = ((long)b * F_ + (f0 - 1)) * FC;
    const long hmax = (long)B_ * F_ * FC - 1;
#pragma unroll 1
    for (int i = 0; i < 33; i++) {
        int idx = i * 64 + L;
        if (idx < 32 * FC) {
            long g = hbase + idx;
            g = g < 0 ? 0 : (g > hmax ? hmax : g);
            bufA[idx] = H[g];
        }
    }
    __syncthreads();

    // ---- phase 3+4 in two tiles (keeps peak live regs ~90 under the 128 cap) ----
#define P3R(k) float Rr##k = 0.0f, Ri##k = 0.0f;
#define P3F(k) Rr##k = fmaf(h, w[2*(k)], Rr##k); Ri##k = fmaf(h, w[2*(k)+1], Ri##k);
#define P3X(k) { float xr_ = Nr##k * Rr##k - Ni##k * Ri##k; \
                 Ni##k = Nr##k * Ri##k + Ni##k * Rr##k; Nr##k = xr_; }
    {
        REPA(P3R)
#pragma unroll 1
        for (int kap = 0; kap < FC; kap++) {
            float h = bufA[p * FC + kap];
            const float* w = ws + W_OFF + kap * KP + off;
            REPA(P3F)
        }
        REPA(P3X)
    }
    {
        REPB(P3R)
#pragma unroll 1
        for (int kap = 0; kap < FC; kap++) {
            float h = bufA[p * FC + kap];
            const float* w = ws + W_OFF + kap * KP + off;
            REPB(P3F)
        }
        REPB(P3X)
    }
#undef P3R
#undef P3F
#undef P3X
    __syncthreads();                      // H dead; bufA becomes obuf (stride 65)

    // ---- phase 5: y[t] = E[t].X (partial), combine across pair via shfl_xor ----
#define P5(k) ya[(k) & 3]       = fmaf(Nr##k, e[2*(k)],   ya[(k) & 3]); \
              ya[((k) + 2) & 3] = fmaf(Ni##k, e[2*(k)+1], ya[((k) + 2) & 3]);
#pragma unroll 1
    for (int t = 0; t < 64; t++) {
        const float* e = ws + E_OFF + t * KP + off;
        float ya[4] = {0.f, 0.f, 0.f, 0.f};
        REP25(P5)
        float y = (ya[0] + ya[1]) + (ya[2] + ya[3]);
        y += __shfl_xor(y, 1);                        // full y for frame p
        if (own && p >= 1 && p - 1 < nf) bufA[(p - 1) * 65 + t] = y;
    }
#pragma unroll 1
    for (int t = 64; t < 97; t++) {
        const float* e = ws + E_OFF + t * KP + off;
        float ya[4] = {0.f, 0.f, 0.f, 0.f};
        REP25(P5)
        float y = (ya[0] + ya[1]) + (ya[2] + ya[3]);
        y += __shfl_xor(y, 1);

        int r = t - 64;
        float tp = __shfl_up(y, 2);                   // pair p-1's tail sample
        if (own && p >= 1 && p - 1 < nf) bufA[(p - 1) * 65 + r] += tp;
        if (own && fMine == F_ - 1)                   // global last frame's tail
            out[(long)b * OUT_LEN + (long)(F_ - 1) * FRAME + t] = y;
    }
#undef P5
    __syncthreads();

    // ---- phase 6: coalesced 256B wave stores ----
    long obase2 = (long)b * OUT_LEN + (long)f0 * FRAME;
#pragma unroll 1
    for (int i = 0; i < nf; i++) {
        out[obase2 + (long)i * 64 + L] = bufA[i * 65 + L];
    }
}

extern "C" void kernel_launch(void* const* d_in, const int* in_sizes, int n_in,
                              void* d_out, int out_size, void* d_ws, size_t ws_size,
                              hipStream_t stream) {
    const float* H     = (const float*)d_in[0];   // (32, 4000, 65) fp32
    const float* noise = (const float*)d_in[1];   // (32, 4000, 64) fp32
    float* out = (float*)d_out;                   // (32, 256033) fp32
    float* ws  = (float*)d_ws;                    // matrices, 226*100 floats

    fn_init<<<(N_INIT + 255) / 256, 256, 0, stream>>>(ws);
    fn_main_kernel<<<B_ * NCHUNK, 64, 0, stream>>>(H, noise, ws, out);
}

// Round 7
// 249.486 us; speedup vs baseline: 2.0611x; 2.0611x over previous
//
#include <hip/hip_runtime.h>
#include <math.h>

// ---------------- problem constants ----------------
#define FC     65            // freq bins in H
#define NB     97            // output samples per frame (lossy irfft n)
#define KB     49            // bins actually used = NB//2+1
#define FRAME  64
#define B_     32
#define F_     4000
#define OUT_LEN ((F_ - 1) * FRAME + NB)   // 256033
#define CHUNK  63                          // OUTPUT frames per block (lane0 redundant)
#define NCHUNK 64
#define KP     100                         // padded row stride (16B-aligned rows)

// ws layout (floats), rows stacked contiguously (226 rows x 100):
//   D: rows 0..63    row j:   (cos,sin)(-2*pi*k*j/192), k=0..48, pads 98/99=0
//   W: rows 64..128  row kap: complex W matrix, pads 0
//   E: rows 129..225 row t:   (Er,Ei) with gain folded, pads 0
#define D_OFF  0
#define W_OFF  (64 * KP)
#define E_OFF  (129 * KP)

#define N_D    (64 * KB)
#define N_E    (97 * KB)
#define N_W    (65 * KB)
#define N_ALL  (N_D + N_E + N_W)
#define N_PADZ (226 * 2)
#define N_INIT (N_ALL + N_PADZ)

// ---------- init kernel; W via fp64 recurrences (no libm in loop) ----------
__global__ void fn_init(float* __restrict__ ws) {
    int tid = blockIdx.x * blockDim.x + threadIdx.x;
    if (tid < N_D) {
        int j = tid / KB, k = tid % KB;
        double x = -(double)(k * j) / 96.0;
        ws[D_OFF + j * KP + 2 * k]     = (float)cospi(x);
        ws[D_OFF + j * KP + 2 * k + 1] = (float)sinpi(x);
    } else if (tid < N_D + N_E) {
        int t2 = tid - N_D;
        int t = t2 / KB, k = t2 % KB;
        double g = 0.01 / 97.0;
        double x = 2.0 * (double)(k * t) / 97.0;
        ws[E_OFF + t * KP + 2 * k]     = (float)(g * (k == 0 ? 1.0 : 2.0) * cospi(x));
        ws[E_OFF + t * KP + 2 * k + 1] = (float)(k == 0 ? 0.0 : -2.0 * g * sinpi(x));
    } else if (tid < N_ALL) {
        int t2 = tid - (N_D + N_E);
        int kap = t2 / KB, k = t2 % KB;
        double sr_ = cospi(-(double)k / 96.0), si_ = sinpi(-(double)k / 96.0);
        double er = 1.0, ei = 0.0;
        double C2 = 2.0 * cospi(2.0 * (double)kap / 129.0);
        double c_prev = cospi(-130.0 * (double)kap / 129.0);
        double c_cur  = cospi(-128.0 * (double)kap / 129.0);
        double U2 = 2.0 * cospi(2.0 / 129.0);
        double u_prev = cospi(2.0 / 129.0);
        double u_cur  = 1.0;
        double accr = 0.0, acci = 0.0;
        for (int m = 0; m < 129; m++) {
            double win = 0.5 * (1.0 - u_cur);
            double a = win * (1.0 / 129.0);
            if (kap) a *= 2.0 * c_cur;
            accr += a * er; acci += a * ei;
            double un = U2 * u_cur - u_prev; u_prev = u_cur; u_cur = un;
            double cn = C2 * c_cur - c_prev; c_prev = c_cur; c_cur = cn;
            double e2r = er * sr_ - ei * si_;
            double e2i = er * si_ + ei * sr_;
            er = e2r; ei = e2i;
        }
        ws[W_OFF + kap * KP + 2 * k]     = (float)accr;
        ws[W_OFF + kap * KP + 2 * k + 1] = (float)acci;
    } else if (tid < N_INIT) {
        int z = tid - N_ALL;
        ws[(z >> 1) * KP + 98 + (z & 1)] = 0.0f;
    }
}

// Named scalars with LITERAL indices (hipcc SROA runs before unrolling;
// loop-variable-indexed arrays land in scratch — proven rounds 3-5).
#define REPT_A(M) M(0) M(1) M(2) M(3) M(4) M(5) M(6) M(7) M(8) M(9) M(10) M(11) \
  M(12) M(13) M(14) M(15) M(16) M(17) M(18) M(19) M(20) M(21) M(22) M(23) M(24)
#define REPT_B(M) M(25) M(26) M(27) M(28) M(29) M(30) M(31) M(32) M(33) M(34) M(35) \
  M(36) M(37) M(38) M(39) M(40) M(41) M(42) M(43) M(44) M(45) M(46) M(47) M(48)

// float4 chunk c covers bins (2c, 2c+1); chunks 0..23 = bins 0..47
#define CH24(M) M(0,0,1) M(1,2,3) M(2,4,5) M(3,6,7) M(4,8,9) M(5,10,11) M(6,12,13) \
  M(7,14,15) M(8,16,17) M(9,18,19) M(10,20,21) M(11,22,23) M(12,24,25) M(13,26,27) \
  M(14,28,29) M(15,30,31) M(16,32,33) M(17,34,35) M(18,36,37) M(19,38,39) \
  M(20,40,41) M(21,42,43) M(22,44,45) M(23,46,47)
#define CH12A(M) M(0,0,1) M(1,2,3) M(2,4,5) M(3,6,7) M(4,8,9) M(5,10,11) M(6,12,13) \
  M(7,14,15) M(8,16,17) M(9,18,19) M(10,20,21) M(11,22,23)
#define CHB(M) M(0,25) M(1,26) M(2,27) M(3,28) M(4,29) M(5,30) M(6,31) M(7,32) \
  M(8,33) M(9,34) M(10,35) M(11,36) M(12,37) M(13,38) M(14,39) M(15,40) M(16,41) \
  M(17,42) M(18,43) M(19,44) M(20,45) M(21,46) M(22,47) M(23,48)

// staging: up to 8 rows (200 float4) coalesced global->regs->LDS
#define LOADG(gbase, nf4) { \
    const float4* gp = (const float4*)(gbase); \
    if (L < (nf4))       tA = gp[L]; \
    if (64 + L < (nf4))  tB = gp[64 + L]; \
    if (128 + L < (nf4)) tC = gp[128 + L]; \
    if (192 + L < (nf4)) tD = gp[192 + L]; }
#define PUTLDS(nf4) { \
    if (L < (nf4))       mat4[L] = tA; \
    if (64 + L < (nf4))  mat4[64 + L] = tB; \
    if (128 + L < (nf4)) mat4[128 + L] = tC; \
    if (192 + L < (nf4)) mat4[192 + L] = tD; }

// ---------- main: 1 wave/block, 64 frames (63 output + 1 redundant) ----------
__launch_bounds__(64, 2)
__global__ void fn_main_kernel(const float* __restrict__ H,
                               const float* __restrict__ noise,
                               const float* __restrict__ ws,
                               float* __restrict__ out) {
    __shared__ float bufA[64 * 65];                 // noise -> H -> obuf (16.6 KB)
    __shared__ __align__(16) float mat[8 * KP];     // matrix row-group buffer (3.2 KB)
    float4* mat4 = (float4*)mat;

    int bid = blockIdx.x;
    int b = bid >> 6;
    int c = bid & 63;
    int f0 = c * CHUNK;
    int nf = min(CHUNK, F_ - f0);
    int L = threadIdx.x;                  // lane computes frame f0-1+L
    int fMine = f0 - 1 + L;

    // ---- phase 0: stage noise frames f0-1 .. f0+62 (row i, stride 65) ----
    long nbase = ((long)b * F_ + (f0 - 1)) * FRAME;
    const long nmax = (long)B_ * F_ * FRAME - 1;
#pragma unroll 1
    for (int i = 0; i < 64; i++) {
        long g = nbase + (long)i * 64 + L;
        g = g < 0 ? 0 : (g > nmax ? nmax : g);
        float v = 2.0f * noise[g] - 1.0f;
        if (c == 0 && i == 0) v = 0.0f;   // frame -1: force N=0 -> X=0
        bufA[i * 65 + L] = v;
    }
    __syncthreads();

    // ---- X state: 98 named scalar registers ----
#define DECLX(k) float Nr##k = 0.0f, Ni##k = 0.0f;
    REPT_A(DECLX) REPT_B(DECLX)
#undef DECLX

    float4 tA, tB, tC, tD;

    // ---- phase 1: N = DFT rows j=0..63, D streamed in 8-row LDS groups ----
    LOADG(ws + D_OFF, 200)
#pragma unroll 1
    for (int g = 0; g < 8; g++) {
        PUTLDS(200)
        if (g + 1 < 8) LOADG(ws + D_OFF + (g + 1) * 8 * KP, 200)
        __syncthreads();
#pragma unroll 1
        for (int r = 0; r < 8; r++) {
            int j = g * 8 + r;
            float n = bufA[L * 65 + j];
            const float4* row4 = (const float4*)(mat + r * KP);
#define P1C(c,b0,b1) { float4 v = row4[c]; \
    Nr##b0 = fmaf(n, v.x, Nr##b0); Ni##b0 = fmaf(n, v.y, Ni##b0); \
    Nr##b1 = fmaf(n, v.z, Nr##b1); Ni##b1 = fmaf(n, v.w, Ni##b1); }
            CH24(P1C)
#undef P1C
            { float2 v = *(const float2*)(mat + r * KP + 96);
              Nr48 = fmaf(n, v.x, Nr48); Ni48 = fmaf(n, v.y, Ni48); }
        }
        __syncthreads();
    }

    // ---- phase 2: stage H (linear copy, 64 frames x 65 floats) ----
    long hbase = ((long)b * F_ + (f0 - 1)) * FC;
    const long hmax = (long)B_ * F_ * FC - 1;
#pragma unroll 1
    for (int i = 0; i < 65; i++) {
        long g = hbase + (long)i * 64 + L;
        g = g < 0 ? 0 : (g > hmax ? hmax : g);
        bufA[i * 64 + L] = H[g];
    }
    __syncthreads();

    // ---- phase 3+4: R = W.h, X = N*R; two bin-tiles, W streamed twice ----
    {   // tile A: bins 0..24 (row floats 0..49)
#define DECLR(b) float Rr##b = 0.0f, Ri##b = 0.0f;
        REPT_A(DECLR)
#undef DECLR
        LOADG(ws + W_OFF, 200)
#pragma unroll 1
        for (int g = 0; g < 9; g++) {
            int cnt = (g == 8) ? 1 : 8;
            PUTLDS(cnt * 25)
            if (g + 1 < 9) { int c2 = (g + 1 == 8) ? 1 : 8; LOADG(ws + W_OFF + (g + 1) * 8 * KP, c2 * 25) }
            __syncthreads();
#pragma unroll 1
            for (int r = 0; r < cnt; r++) {
                int kap = g * 8 + r;
                float h = bufA[L * FC + kap];
                const float4* row4 = (const float4*)(mat + r * KP);
#define P3A(c,b0,b1) { float4 v = row4[c]; \
    Rr##b0 = fmaf(h, v.x, Rr##b0); Ri##b0 = fmaf(h, v.y, Ri##b0); \
    Rr##b1 = fmaf(h, v.z, Rr##b1); Ri##b1 = fmaf(h, v.w, Ri##b1); }
                CH12A(P3A)
#undef P3A
                { float2 v = *(const float2*)(mat + r * KP + 48);
                  Rr24 = fmaf(h, v.x, Rr24); Ri24 = fmaf(h, v.y, Ri24); }
            }
            __syncthreads();
        }
#define P4(b) { float xr_ = Nr##b * Rr##b - Ni##b * Ri##b; \
                Ni##b = Nr##b * Ri##b + Ni##b * Rr##b; Nr##b = xr_; }
        REPT_A(P4)
#undef P4
    }
    {   // tile B: bins 25..48 (row floats 50..97, float2 reads)
#define DECLR(b) float Rr##b = 0.0f, Ri##b = 0.0f;
        REPT_B(DECLR)
#undef DECLR
        LOADG(ws + W_OFF, 200)
#pragma unroll 1
        for (int g = 0; g < 9; g++) {
            int cnt = (g == 8) ? 1 : 8;
            PUTLDS(cnt * 25)
            if (g + 1 < 9) { int c2 = (g + 1 == 8) ? 1 : 8; LOADG(ws + W_OFF + (g + 1) * 8 * KP, c2 * 25) }
            __syncthreads();
#pragma unroll 1
            for (int r = 0; r < cnt; r++) {
                int kap = g * 8 + r;
                float h = bufA[L * FC + kap];
                const float2* row2 = (const float2*)(mat + r * KP + 50);
#define P3B(i,b) { float2 v = row2[i]; \
    Rr##b = fmaf(h, v.x, Rr##b); Ri##b = fmaf(h, v.y, Ri##b); }
                CHB(P3B)
#undef P3B
            }
            __syncthreads();
        }
#define P4(b) { float xr_ = Nr##b * Rr##b - Ni##b * Ri##b; \
                Ni##b = Nr##b * Ri##b + Ni##b * Rr##b; Nr##b = xr_; }
        REPT_B(P4)
#undef P4
    }
    __syncthreads();                      // H dead; bufA becomes obuf (stride 65)

    // ---- phase 5: y[t] = E[t].X, E streamed; in-wave overlap-add ----
    LOADG(ws + E_OFF, 200)
#pragma unroll 1
    for (int g = 0; g < 13; g++) {
        int cnt = (g == 12) ? 1 : 8;
        PUTLDS(cnt * 25)
        if (g + 1 < 13) { int c2 = (g + 1 == 12) ? 1 : 8; LOADG(ws + E_OFF + (g + 1) * 8 * KP, c2 * 25) }
        __syncthreads();
#pragma unroll 1
        for (int r = 0; r < cnt; r++) {
            int t = g * 8 + r;
            const float4* row4 = (const float4*)(mat + r * KP);
            float y0 = 0.f, y1 = 0.f, y2 = 0.f, y3 = 0.f;
#define P5C(c,b0,b1) { float4 v = row4[c]; \
    y0 = fmaf(Nr##b0, v.x, y0); y1 = fmaf(Ni##b0, v.y, y1); \
    y2 = fmaf(Nr##b1, v.z, y2); y3 = fmaf(Ni##b1, v.w, y3); }
            CH24(P5C)
#undef P5C
            { float2 v = *(const float2*)(mat + r * KP + 96);
              y0 = fmaf(Nr48, v.x, y0); y1 = fmaf(Ni48, v.y, y1); }
            float y = (y0 + y1) + (y2 + y3);

            if (t < 64) {
                if (L) bufA[(L - 1) * 65 + t] = y;
            } else {
                int rr = t - 64;
                float p = __shfl_up(y, 1);            // prev frame's tail sample
                if (L) bufA[(L - 1) * 65 + rr] += p;  // head + prev tail
                if (fMine == F_ - 1)
                    out[(long)b * OUT_LEN + (long)(F_ - 1) * FRAME + t] = y;
            }
        }
        __syncthreads();
    }

    // ---- phase 6: coalesced 256B wave stores ----
    long obase2 = (long)b * OUT_LEN + (long)f0 * FRAME;
#pragma unroll 1
    for (int i = 0; i < nf; i++) {
        out[obase2 + (long)i * 64 + L] = bufA[i * 65 + L];
    }
}

extern "C" void kernel_launch(void* const* d_in, const int* in_sizes, int n_in,
                              void* d_out, int out_size, void* d_ws, size_t ws_size,
                              hipStream_t stream) {
    const float* H     = (const float*)d_in[0];   // (32, 4000, 65) fp32
    const float* noise = (const float*)d_in[1];   // (32, 4000, 64) fp32
    float* out = (float*)d_out;                   // (32, 256033) fp32
    float* ws  = (float*)d_ws;                    // matrices, 226*100 floats

    fn_init<<<(N_INIT + 255) / 256, 256, 0, stream>>>(ws);
    fn_main_kernel<<<B_ * NCHUNK, 64, 0, stream>>>(H, noise, ws, out);
}